// Round 3
// baseline (383.228 us; speedup 1.0000x reference)
//
#include <hip/hip_runtime.h>
#include <math.h>

// Problem constants
#define B_  4
#define T_  2048
#define C_  1024
#define HS_ 64
#define M_  (B_*T_)   // 8192 rows
#define NCAT 192
#define SCALE_ 0.03125f   // C^-0.5

typedef unsigned short ushort_t;
typedef short bf16x8 __attribute__((ext_vector_type(8)));
typedef float f32x4 __attribute__((ext_vector_type(4)));

static __device__ __forceinline__ unsigned short f2bf(float f) {   // RNE (for inputs)
    union { float f; unsigned int u; } c; c.f = f;
    unsigned int u = c.u;
    return (unsigned short)((u + 0x7FFFu + ((u >> 16) & 1u)) >> 16);
}
static __device__ __forceinline__ unsigned short f2bf_fast(float f) { // 2-op round
    union { float f; unsigned int u; } c; c.f = f;
    return (unsigned short)((c.u + 0x8000u) >> 16);
}

// ---------------------------------------------------------------------------
// Kernel 1: W -> wt bf16 transposed [192][1024] (4/thread, 192 blocks).
// Block 0 also zeroes the 512 rowgroup flags (must happen every graph
// iteration: the harness re-poisons the workspace between iterations).
// Stream order publishes the zeroed flags to kernel 2.
// ---------------------------------------------------------------------------
__global__ void wconv_kernel(const float* __restrict__ Wq, const float* __restrict__ Wk,
                             const float* __restrict__ Wv, ushort_t* __restrict__ wt,
                             int* __restrict__ flags) {
    if (blockIdx.x == 0) {
        flags[threadIdx.x] = 0;
        flags[threadIdx.x + 256] = 0;
    }
    int idx = (blockIdx.x * 256 + threadIdx.x) * 4;   // < 192*1024
    int n = idx >> 10;
    int k0 = idx & 1023;
    const float* W = (n < 64) ? Wq : (n < 128) ? Wk : Wv;
    int nn = n & 63;
    ushort_t o0 = f2bf(W[(k0 + 0) * HS_ + nn]);
    ushort_t o1 = f2bf(W[(k0 + 1) * HS_ + nn]);
    ushort_t o2 = f2bf(W[(k0 + 2) * HS_ + nn]);
    ushort_t o3 = f2bf(W[(k0 + 3) * HS_ + nn]);
    uint2 d;
    d.x = (unsigned)o0 | ((unsigned)o1 << 16);
    d.y = (unsigned)o2 | ((unsigned)o3 << 16);
    *(uint2*)(wt + (size_t)n * C_ + k0) = d;
}

// ---------------------------------------------------------------------------
// Kernel 2: FUSED proj + flash. 512 blocks x 512 thr, launch_bounds(512,4)
// forces VGPR<=128; LDS = 48 KB -> exactly 2 blocks/CU -> ALL 512 blocks
// co-resident (spin-sync safe by construction).
//
// Phase 1 (proj): block = rowgroup rg = blockIdx.x (16 rows), 8 waves =
// 8 K-slices of 128, 12 MFMA tiles (Q|K|V x 64 cols), 3-round LDS tree
// reduce, wave 0 writes qws/kws/vt, then releases flags[rg] (agent scope).
//
// Phase 2 (flash): one 16-row q-tile per block, 8 key-slice waves.
// Heavy/light pairing across dispatch rounds: b<256 -> t=64+(b&63),
// b>=256 -> t=63-(b&63) (CU's two resident blocks sum to const work).
// Thread 0 acquire-spins on the rowgroup prefix covering ALL loaded keys
// (incl. masked-out tail rows -> no 0*NaN from poison). Light tiles run
// while proj still executes elsewhere -> flash hides under proj.
// fp32 O/lsum tree-reduced 8->1 via LDS, direct fp32 out write.
// ---------------------------------------------------------------------------
__global__ __launch_bounds__(512, 4) void fused_kernel(const float* __restrict__ x,
    const ushort_t* __restrict__ wt,
    ushort_t* __restrict__ qws, ushort_t* __restrict__ kws, ushort_t* __restrict__ vt,
    int* __restrict__ flags, float* __restrict__ out) {
    __shared__ __align__(16) unsigned char pool[49152];

    int tid  = threadIdx.x;
    int wid  = tid >> 6;
    int lane = tid & 63;
    int qd   = lane >> 4;
    int lq   = lane & 15;

    // ================= Phase 1: projection =================
    {
        f32x4 (*red)[12 * 64] = (f32x4 (*)[12 * 64])pool;   // 4 slots, 48 KB
        int r0 = blockIdx.x * 16;

        f32x4 acc[12];
        #pragma unroll
        for (int i = 0; i < 12; i++) acc[i] = (f32x4){0.f,0.f,0.f,0.f};

        const float*    xp = x  + (size_t)(r0 + lq) * C_ + wid * 128 + qd * 8;
        const ushort_t* wp = wt + (size_t)lq * C_ + wid * 128 + qd * 8;

        #pragma unroll
        for (int i = 0; i < 4; i++) {
            float4 a0 = *(const float4*)(xp + i * 32);
            float4 a1 = *(const float4*)(xp + i * 32 + 4);
            union { bf16x8 v; ushort_t u[8]; } af;
            af.u[0] = f2bf(a0.x); af.u[1] = f2bf(a0.y); af.u[2] = f2bf(a0.z); af.u[3] = f2bf(a0.w);
            af.u[4] = f2bf(a1.x); af.u[5] = f2bf(a1.y); af.u[6] = f2bf(a1.z); af.u[7] = f2bf(a1.w);
            #pragma unroll
            for (int nt = 0; nt < 12; nt++) {
                bf16x8 bv = *(const bf16x8*)(wp + (size_t)nt * 16 * C_ + i * 32);
                acc[nt] = __builtin_amdgcn_mfma_f32_16x16x32_bf16(af.v, bv, acc[nt], 0, 0, 0);
            }
        }

        // tree reduce 8 -> 4 -> 2 -> 1 through 4 LDS slots
        if (wid >= 4) {
            #pragma unroll
            for (int nt = 0; nt < 12; nt++) red[wid - 4][nt * 64 + lane] = acc[nt];
        }
        __syncthreads();
        if (wid < 4) {
            #pragma unroll
            for (int nt = 0; nt < 12; nt++) acc[nt] += red[wid][nt * 64 + lane];
        }
        __syncthreads();
        if (wid == 2 || wid == 3) {
            #pragma unroll
            for (int nt = 0; nt < 12; nt++) red[wid][nt * 64 + lane] = acc[nt];
        }
        __syncthreads();
        if (wid < 2) {
            #pragma unroll
            for (int nt = 0; nt < 12; nt++) acc[nt] += red[wid + 2][nt * 64 + lane];
        }
        __syncthreads();
        if (wid == 1) {
            #pragma unroll
            for (int nt = 0; nt < 12; nt++) red[0][nt * 64 + lane] = acc[nt];
        }
        __syncthreads();
        if (wid == 0) {
            #pragma unroll
            for (int nt = 0; nt < 12; nt++) {
                acc[nt] += red[0][nt * 64 + lane];
                int outn = nt >> 2;            // 0=Q 1=K 2=V
                int col  = (nt & 3) * 16 + lq; // 0..63
                #pragma unroll
                for (int r = 0; r < 4; r++) {
                    int row = r0 + qd * 4 + r;
                    float v = acc[nt][r];
                    if (outn == 0) v *= SCALE_;           // pre-scale Q
                    ushort_t val = f2bf(v);
                    if (outn == 0)      qws[(size_t)row * HS_ + col] = val;
                    else if (outn == 1) kws[(size_t)row * HS_ + col] = val;
                    else {
                        int b = row >> 11, t = row & 2047;
                        vt[((size_t)b * 64 + col) * T_ + t] = val;
                    }
                }
            }
            // publish this rowgroup (only wave 0 wrote globals; fence is
            // executed by the same wave, then release-store the flag)
            __threadfence();
            if (tid == 0)
                __hip_atomic_store(&flags[blockIdx.x], 1, __ATOMIC_RELEASE,
                                   __HIP_MEMORY_SCOPE_AGENT);
        }
    }

    // ================= Phase 2: flash attention =================
    int bb    = (int)blockIdx.x;
    int half  = bb >> 8;               // 0 = heavy tiles, 1 = light tiles
    int bl    = bb & 255;
    int fbatch = bl >> 6;
    int a     = bl & 63;
    int tile  = half ? (63 - a) : (64 + a);
    int q0    = tile * 16;
    int qrow  = q0 + lq;
    int grow  = fbatch * T_ + qrow;
    int nU    = (tile + 4) >> 2;       // 64-key units covering keys [0, q0+16)
    int need  = nU * 4 - 1;            // last rowgroup actually LOADED (masked tail incl.)
    if (need > 127) need = 127;

    // wait for all producing rowgroups of this batch (prefix 0..need)
    if (tid == 0) {
        const int* fb = flags + fbatch * 128;
        int i = 0;
        while (i <= need) {
            if (__hip_atomic_load(&fb[i], __ATOMIC_ACQUIRE,
                                  __HIP_MEMORY_SCOPE_AGENT) != 0) i++;
        }
    }
    __syncthreads();    // also separates proj's LDS use from flash's pw use

    int ws = wid;       // key-slice 0..7

    bf16x8 qf[2];
    #pragma unroll
    for (int st = 0; st < 2; st++)
        qf[st] = *(const bf16x8*)(qws + (size_t)grow * HS_ + st * 32 + qd * 8);

    float lsum = 0.f;
    f32x4 O[4];
    #pragma unroll
    for (int nt = 0; nt < 4; nt++) O[nt] = (f32x4){0.f,0.f,0.f,0.f};

    ushort_t* pw = (ushort_t*)pool + wid * 1152 + lq * 72;   // stride 72 bf16
    const ushort_t* kp    = kws + (size_t)fbatch * T_ * HS_;
    const ushort_t* vbase = vt  + (size_t)fbatch * 64 * T_;

    for (int u = ws; u < nU; u += 8) {
        int kb = u * 64;

        // batched K loads (8 x 16B, independent)
        bf16x8 kf[8];
        #pragma unroll
        for (int sub = 0; sub < 4; sub++)
            #pragma unroll
            for (int st = 0; st < 2; st++)
                kf[sub * 2 + st] = *(const bf16x8*)(kp + (size_t)(kb + sub * 16 + lq) * HS_ + st * 32 + qd * 8);

        // S^T = K . Q^T (Q pre-scaled): 4 sub-tiles of 16 keys
        f32x4 S[4];
        #pragma unroll
        for (int sub = 0; sub < 4; sub++) {
            f32x4 s = (f32x4){0.f,0.f,0.f,0.f};
            #pragma unroll
            for (int st = 0; st < 2; st++)
                s = __builtin_amdgcn_mfma_f32_16x16x32_bf16(kf[sub * 2 + st], qf[st], s, 0, 0, 0);
            S[sub] = s;
        }

        // P = exp(S); mask only when this 64-key unit can cross the diagonal
        if (kb + 64 > q0) {
            #pragma unroll
            for (int sub = 0; sub < 4; sub++)
                #pragma unroll
                for (int r = 0; r < 4; r++) {
                    int key = kb + sub * 16 + qd * 4 + r;
                    float pv = (key <= qrow) ? __expf(S[sub][r]) : 0.f;
                    S[sub][r] = pv;
                    lsum += pv;
                }
        } else {
            #pragma unroll
            for (int sub = 0; sub < 4; sub++)
                #pragma unroll
                for (int r = 0; r < 4; r++) {
                    float pv = __expf(S[sub][r]);
                    S[sub][r] = pv;
                    lsum += pv;
                }
        }

        // P^T: C-layout -> LDS (4x b64 writes); kf/S die here
        #pragma unroll
        for (int sub = 0; sub < 4; sub++) {
            uint2 d;
            d.x = (unsigned)f2bf_fast(S[sub][0]) | ((unsigned)f2bf_fast(S[sub][1]) << 16);
            d.y = (unsigned)f2bf_fast(S[sub][2]) | ((unsigned)f2bf_fast(S[sub][3]) << 16);
            *(uint2*)(pw + sub * 16 + qd * 4) = d;
        }
        __builtin_amdgcn_sched_barrier(0);   // keep V-phase from inflating K-phase regs

        bf16x8 pf0 = *(const bf16x8*)(pw + qd * 8);
        bf16x8 pf1 = *(const bf16x8*)(pw + 32 + qd * 8);

        // O^T += V^T . P^T in two 4-register V halves (caps live VGPRs)
        #pragma unroll
        for (int h = 0; h < 2; h++) {
            bf16x8 vf[4];
            #pragma unroll
            for (int nt = 0; nt < 2; nt++)
                #pragma unroll
                for (int kk = 0; kk < 2; kk++)
                    vf[nt * 2 + kk] = *(const bf16x8*)(vbase + ((size_t)(h * 2 + nt) * 16 + lq) * T_ + kb + kk * 32 + qd * 8);
            #pragma unroll
            for (int nt = 0; nt < 2; nt++) {
                O[h * 2 + nt] = __builtin_amdgcn_mfma_f32_16x16x32_bf16(vf[nt * 2 + 0], pf0, O[h * 2 + nt], 0, 0, 0);
                O[h * 2 + nt] = __builtin_amdgcn_mfma_f32_16x16x32_bf16(vf[nt * 2 + 1], pf1, O[h * 2 + nt], 0, 0, 0);
            }
        }
    }

    // ---- cross-wave fp32 reduction, 8 -> 4 -> 2 -> 1 ----
    f32x4* red  = (f32x4*)pool;                  // 4 slots x 256 f32x4 (16 KB)
    float* lred = (float*)(pool + 16384);        // 4 slots x 64 f32
    __syncthreads();                             // pw fully dead block-wide
    if (ws >= 4) {
        f32x4* rs = red + (size_t)(ws - 4) * 256;
        #pragma unroll
        for (int nt = 0; nt < 4; nt++) rs[nt * 64 + lane] = O[nt];
        lred[(ws - 4) * 64 + lane] = lsum;
    }
    __syncthreads();
    if (ws < 4) {
        f32x4* rs = red + (size_t)ws * 256;
        #pragma unroll
        for (int nt = 0; nt < 4; nt++) O[nt] += rs[nt * 64 + lane];
        lsum += lred[ws * 64 + lane];
    }
    __syncthreads();
    if (ws == 2 || ws == 3) {
        f32x4* rs = red + (size_t)(ws - 2) * 256;
        #pragma unroll
        for (int nt = 0; nt < 4; nt++) rs[nt * 64 + lane] = O[nt];
        lred[(ws - 2) * 64 + lane] = lsum;
    }
    __syncthreads();
    if (ws < 2) {
        f32x4* rs = red + (size_t)ws * 256;
        #pragma unroll
        for (int nt = 0; nt < 4; nt++) O[nt] += rs[nt * 64 + lane];
        lsum += lred[ws * 64 + lane];
    }
    __syncthreads();
    if (ws == 1) {
        f32x4* rs = red;
        #pragma unroll
        for (int nt = 0; nt < 4; nt++) rs[nt * 64 + lane] = O[nt];
        lred[lane] = lsum;
    }
    __syncthreads();
    if (ws == 0) {
        f32x4* rs = red;
        #pragma unroll
        for (int nt = 0; nt < 4; nt++) O[nt] += rs[nt * 64 + lane];
        lsum += lred[lane];
        // fold the 4 qd partial row-sums -> full denominator per row
        lsum += __shfl_xor(lsum, 16, 64);
        lsum += __shfl_xor(lsum, 32, 64);
        float li = 1.f / lsum;
        #pragma unroll
        for (int nt = 0; nt < 4; nt++) {
            f32x4 o = O[nt] * li;
            *(f32x4*)(out + (size_t)grow * HS_ + nt * 16 + qd * 4) = o;
        }
    }
}

// ---------------------------------------------------------------------------
extern "C" void kernel_launch(void* const* d_in, const int* in_sizes, int n_in,
                              void* d_out, int out_size, void* d_ws, size_t ws_size,
                              hipStream_t stream) {
    const float* x  = (const float*)d_in[0];
    const float* Wq = (const float*)d_in[1];
    const float* Wk = (const float*)d_in[2];
    const float* Wv = (const float*)d_in[3];
    float* out = (float*)d_out;

    ushort_t* wt  = (ushort_t*)d_ws;                    // 192*1024
    ushort_t* qws = wt  + (size_t)NCAT * C_;            // 8192*64
    ushort_t* kws = qws + (size_t)M_ * HS_;
    ushort_t* vt  = kws + (size_t)M_ * HS_;
    int* flags    = (int*)(vt + (size_t)M_ * HS_);      // 512 ints

    wconv_kernel<<<NCAT * C_ / (256 * 4), 256, 0, stream>>>(Wq, Wk, Wv, wt, flags);
    fused_kernel<<<512, 512, 0, stream>>>(x, wt, qws, kws, vt, flags, out);
}

// Round 5
// 122.078 us; speedup vs baseline: 3.1392x; 3.1392x over previous
//
#include <hip/hip_runtime.h>
#include <math.h>

// Problem constants
#define B_  4
#define T_  2048
#define C_  1024
#define HS_ 64
#define M_  (B_*T_)   // 8192 rows
#define NCAT 192
#define SCALE_ 0.03125f   // C^-0.5

typedef unsigned short ushort_t;
typedef short bf16x8 __attribute__((ext_vector_type(8)));
typedef float f32x4 __attribute__((ext_vector_type(4)));

static __device__ __forceinline__ unsigned short f2bf(float f) {   // RNE (for inputs)
    union { float f; unsigned int u; } c; c.f = f;
    unsigned int u = c.u;
    return (unsigned short)((u + 0x7FFFu + ((u >> 16) & 1u)) >> 16);
}
static __device__ __forceinline__ unsigned short f2bf_fast(float f) { // 2-op round
    union { float f; unsigned int u; } c; c.f = f;
    return (unsigned short)((c.u + 0x8000u) >> 16);
}

// ---------------------------------------------------------------------------
// Kernel 1: W -> wt bf16 transposed [192][1024] (4/thread, 192 blocks).
// ---------------------------------------------------------------------------
__global__ void wconv_kernel(const float* __restrict__ Wq, const float* __restrict__ Wk,
                             const float* __restrict__ Wv, ushort_t* __restrict__ wt) {
    int idx = (blockIdx.x * 256 + threadIdx.x) * 4;   // < 192*1024
    int n = idx >> 10;
    int k0 = idx & 1023;
    const float* W = (n < 64) ? Wq : (n < 128) ? Wk : Wv;
    int nn = n & 63;
    ushort_t o0 = f2bf(W[(k0 + 0) * HS_ + nn]);
    ushort_t o1 = f2bf(W[(k0 + 1) * HS_ + nn]);
    ushort_t o2 = f2bf(W[(k0 + 2) * HS_ + nn]);
    ushort_t o3 = f2bf(W[(k0 + 3) * HS_ + nn]);
    uint2 d;
    d.x = (unsigned)o0 | ((unsigned)o1 << 16);
    d.y = (unsigned)o2 | ((unsigned)o3 << 16);
    *(uint2*)(wt + (size_t)n * C_ + k0) = d;
}

// ---------------------------------------------------------------------------
// Kernel 2: QKV projection, ONE PASS over x. Block = 512 thr = 8 waves =
// 8 K-slices of 128; wave = 16 rows x ALL 192 cols (12 MFMA tiles).
// 3-round LDS tree reduce (49 KB). grid 512 blocks (2/CU).
// Q pre-scaled. V transposed [b][d][t].  (Verified R1 structure.)
// ---------------------------------------------------------------------------
__global__ __launch_bounds__(512, 4) void proj_kernel(const float* __restrict__ x,
    const ushort_t* __restrict__ wt,
    ushort_t* __restrict__ qws, ushort_t* __restrict__ kws, ushort_t* __restrict__ vt) {
    __shared__ __align__(16) f32x4 red[4][12 * 64];   // 49 KB

    int tid  = threadIdx.x;
    int wid  = tid >> 6;       // K-slice 0..7
    int lane = tid & 63;
    int qd   = lane >> 4;
    int lq   = lane & 15;
    int r0   = blockIdx.x * 16;    // 512 rowgroups of 16

    f32x4 acc[12];
    #pragma unroll
    for (int i = 0; i < 12; i++) acc[i] = (f32x4){0.f,0.f,0.f,0.f};

    const float*    xp = x  + (size_t)(r0 + lq) * C_ + wid * 128 + qd * 8;
    const ushort_t* wp = wt + (size_t)lq * C_ + wid * 128 + qd * 8;

    #pragma unroll
    for (int i = 0; i < 4; i++) {
        float4 a0 = *(const float4*)(xp + i * 32);
        float4 a1 = *(const float4*)(xp + i * 32 + 4);
        union { bf16x8 v; ushort_t u[8]; } af;
        af.u[0] = f2bf(a0.x); af.u[1] = f2bf(a0.y); af.u[2] = f2bf(a0.z); af.u[3] = f2bf(a0.w);
        af.u[4] = f2bf(a1.x); af.u[5] = f2bf(a1.y); af.u[6] = f2bf(a1.z); af.u[7] = f2bf(a1.w);
        #pragma unroll
        for (int nt = 0; nt < 12; nt++) {
            bf16x8 bv = *(const bf16x8*)(wp + (size_t)nt * 16 * C_ + i * 32);
            acc[nt] = __builtin_amdgcn_mfma_f32_16x16x32_bf16(af.v, bv, acc[nt], 0, 0, 0);
        }
    }

    // tree reduce 8 -> 4 -> 2 -> 1 through 4 LDS slots
    if (wid >= 4) {
        #pragma unroll
        for (int nt = 0; nt < 12; nt++) red[wid - 4][nt * 64 + lane] = acc[nt];
    }
    __syncthreads();
    if (wid < 4) {
        #pragma unroll
        for (int nt = 0; nt < 12; nt++) acc[nt] += red[wid][nt * 64 + lane];
    }
    __syncthreads();
    if (wid == 2 || wid == 3) {
        #pragma unroll
        for (int nt = 0; nt < 12; nt++) red[wid][nt * 64 + lane] = acc[nt];
    }
    __syncthreads();
    if (wid < 2) {
        #pragma unroll
        for (int nt = 0; nt < 12; nt++) acc[nt] += red[wid + 2][nt * 64 + lane];
    }
    __syncthreads();
    if (wid == 1) {
        #pragma unroll
        for (int nt = 0; nt < 12; nt++) red[0][nt * 64 + lane] = acc[nt];
    }
    __syncthreads();
    if (wid == 0) {
        #pragma unroll
        for (int nt = 0; nt < 12; nt++) {
            acc[nt] += red[0][nt * 64 + lane];
            int outn = nt >> 2;            // 0=Q 1=K 2=V
            int col  = (nt & 3) * 16 + lq; // 0..63
            #pragma unroll
            for (int r = 0; r < 4; r++) {
                int row = r0 + qd * 4 + r;
                float v = acc[nt][r];
                if (outn == 0) v *= SCALE_;           // pre-scale Q
                ushort_t val = f2bf(v);
                if (outn == 0)      qws[(size_t)row * HS_ + col] = val;
                else if (outn == 1) kws[(size_t)row * HS_ + col] = val;
                else {
                    int b = row >> 11, t = row & 2047;
                    vt[((size_t)b * 64 + col) * T_ + t] = val;
                }
            }
        }
    }
}

// ---------------------------------------------------------------------------
// Kernel 3: balanced-pair causal flash (verified R1 structure) + setprio
// around MFMA clusters (T5: k-loop has no block barrier -> 16 independent
// waves/CU at different phases, the regime where setprio measured +4-7%).
// Block = 1024 thr = 16 waves, grid (64 pairs, 4 batches) = 256 blocks.
// Pair (p, 127-p) of 16-row q-tiles: exactly 16*129 keys per block.
// fp32 O/lsum tree-reduced 8->1 per tile via LDS, direct fp32 out write.
// ---------------------------------------------------------------------------
__global__ __launch_bounds__(1024) void flash_kernel(const ushort_t* __restrict__ qws,
    const ushort_t* __restrict__ kws, const ushort_t* __restrict__ vt,
    float* __restrict__ out) {
    // pool: during k-loop = per-wave Pw[16][16*72] bf16 (36864 B);
    // after k-loop (sync'd) = f32x4 red[8][4*64] (32768 B) + float lred[8][64]
    __shared__ __align__(16) unsigned char pool[36864];

    int tid  = threadIdx.x;
    int wid  = tid >> 6;
    int lane = tid & 63;
    int qd   = lane >> 4;
    int lq   = lane & 15;
    int ts   = wid >> 3;      // 0 = tile p, 1 = tile 127-p
    int ws   = wid & 7;       // key-slice 0..7

    int batch = blockIdx.y;
    int p     = blockIdx.x;
    int tile  = ts ? (127 - p) : p;
    int q0    = tile * 16;
    int qrow  = q0 + lq;
    int grow  = batch * T_ + qrow;
    int nU    = (q0 + 16 + 63) >> 6;    // 64-key units covering keys [0, q0+16)

    bf16x8 qf[2];
    #pragma unroll
    for (int st = 0; st < 2; st++)
        qf[st] = *(const bf16x8*)(qws + (size_t)grow * HS_ + st * 32 + qd * 8);

    float lsum = 0.f;
    f32x4 O[4];
    #pragma unroll
    for (int nt = 0; nt < 4; nt++) O[nt] = (f32x4){0.f,0.f,0.f,0.f};

    ushort_t* pw = (ushort_t*)pool + wid * 1152 + lq * 72;   // stride 72 bf16
    const ushort_t* kp    = kws + (size_t)batch * T_ * HS_;
    const ushort_t* vbase = vt  + (size_t)batch * 64 * T_;

    for (int u = ws; u < nU; u += 8) {
        int kb = u * 64;

        // batched K loads (8 x 16B, independent)
        bf16x8 kf[8];
        #pragma unroll
        for (int sub = 0; sub < 4; sub++)
            #pragma unroll
            for (int st = 0; st < 2; st++)
                kf[sub * 2 + st] = *(const bf16x8*)(kp + (size_t)(kb + sub * 16 + lq) * HS_ + st * 32 + qd * 8);

        // S^T = K . Q^T (Q pre-scaled): 4 sub-tiles of 16 keys
        f32x4 S[4];
        __builtin_amdgcn_s_setprio(1);
        #pragma unroll
        for (int sub = 0; sub < 4; sub++) {
            f32x4 s = (f32x4){0.f,0.f,0.f,0.f};
            #pragma unroll
            for (int st = 0; st < 2; st++)
                s = __builtin_amdgcn_mfma_f32_16x16x32_bf16(kf[sub * 2 + st], qf[st], s, 0, 0, 0);
            S[sub] = s;
        }
        __builtin_amdgcn_s_setprio(0);

        // V loads issued here so they fly under exp + LDS roundtrip
        bf16x8 vf[8];
        #pragma unroll
        for (int nt = 0; nt < 4; nt++)
            #pragma unroll
            for (int kk = 0; kk < 2; kk++)
                vf[nt * 2 + kk] = *(const bf16x8*)(vbase + ((size_t)nt * 16 + lq) * T_ + kb + kk * 32 + qd * 8);

        // P = exp(S); mask only when this 64-key unit can cross the diagonal
        if (kb + 64 > q0) {
            #pragma unroll
            for (int sub = 0; sub < 4; sub++)
                #pragma unroll
                for (int r = 0; r < 4; r++) {
                    int key = kb + sub * 16 + qd * 4 + r;
                    float pv = (key <= qrow) ? __expf(S[sub][r]) : 0.f;
                    S[sub][r] = pv;
                    lsum += pv;
                }
        } else {
            #pragma unroll
            for (int sub = 0; sub < 4; sub++)
                #pragma unroll
                for (int r = 0; r < 4; r++) {
                    float pv = __expf(S[sub][r]);
                    S[sub][r] = pv;
                    lsum += pv;
                }
        }

        // P^T: C-layout -> LDS (4x b64 writes) -> B-layout (2x b128 reads)
        #pragma unroll
        for (int sub = 0; sub < 4; sub++) {
            uint2 d;
            d.x = (unsigned)f2bf_fast(S[sub][0]) | ((unsigned)f2bf_fast(S[sub][1]) << 16);
            d.y = (unsigned)f2bf_fast(S[sub][2]) | ((unsigned)f2bf_fast(S[sub][3]) << 16);
            *(uint2*)(pw + sub * 16 + qd * 4) = d;
        }
        bf16x8 pf0 = *(const bf16x8*)(pw + qd * 8);
        bf16x8 pf1 = *(const bf16x8*)(pw + 32 + qd * 8);

        // O^T += V^T . P^T (K-dim = 64 keys = 2 MFMA k-steps)
        __builtin_amdgcn_s_setprio(1);
        #pragma unroll
        for (int nt = 0; nt < 4; nt++) {
            O[nt] = __builtin_amdgcn_mfma_f32_16x16x32_bf16(vf[nt * 2 + 0], pf0, O[nt], 0, 0, 0);
            O[nt] = __builtin_amdgcn_mfma_f32_16x16x32_bf16(vf[nt * 2 + 1], pf1, O[nt], 0, 0, 0);
        }
        __builtin_amdgcn_s_setprio(0);
    }

    // ---- cross-wave fp32 reduction, 8 -> 4 -> 2 -> 1 per tile ----
    f32x4* red  = (f32x4*)pool;                  // 8 slots x 256 f32x4
    float* lred = (float*)(pool + 32768);        // 8 slots x 64 f32
    __syncthreads();                             // Pw fully dead block-wide
    if (ws >= 4) {
        int sl = ts * 4 + (ws - 4);
        f32x4* rs = red + (size_t)sl * 256;
        #pragma unroll
        for (int nt = 0; nt < 4; nt++) rs[nt * 64 + lane] = O[nt];
        lred[sl * 64 + lane] = lsum;
    }
    __syncthreads();
    if (ws < 4) {
        int sl = ts * 4 + ws;
        f32x4* rs = red + (size_t)sl * 256;
        #pragma unroll
        for (int nt = 0; nt < 4; nt++) O[nt] += rs[nt * 64 + lane];
        lsum += lred[sl * 64 + lane];
    }
    __syncthreads();
    if (ws == 2 || ws == 3) {
        int sl = ts * 4 + (ws - 2);
        f32x4* rs = red + (size_t)sl * 256;
        #pragma unroll
        for (int nt = 0; nt < 4; nt++) rs[nt * 64 + lane] = O[nt];
        lred[sl * 64 + lane] = lsum;
    }
    __syncthreads();
    if (ws < 2) {
        int sl = ts * 4 + ws;
        f32x4* rs = red + (size_t)sl * 256;
        #pragma unroll
        for (int nt = 0; nt < 4; nt++) O[nt] += rs[nt * 64 + lane];
        lsum += lred[sl * 64 + lane];
    }
    __syncthreads();
    if (ws == 1) {
        int sl = ts * 4;
        f32x4* rs = red + (size_t)sl * 256;
        #pragma unroll
        for (int nt = 0; nt < 4; nt++) rs[nt * 64 + lane] = O[nt];
        lred[sl * 64 + lane] = lsum;
    }
    __syncthreads();
    if (ws == 0) {
        int sl = ts * 4;
        f32x4* rs = red + (size_t)sl * 256;
        #pragma unroll
        for (int nt = 0; nt < 4; nt++) O[nt] += rs[nt * 64 + lane];
        lsum += lred[sl * 64 + lane];
        // fold the 4 qd partial row-sums -> full denominator per row
        lsum += __shfl_xor(lsum, 16, 64);
        lsum += __shfl_xor(lsum, 32, 64);
        float li = 1.f / lsum;
        #pragma unroll
        for (int nt = 0; nt < 4; nt++) {
            f32x4 o = O[nt] * li;
            *(f32x4*)(out + (size_t)grow * HS_ + nt * 16 + qd * 4) = o;
        }
    }
}

// ---------------------------------------------------------------------------
extern "C" void kernel_launch(void* const* d_in, const int* in_sizes, int n_in,
                              void* d_out, int out_size, void* d_ws, size_t ws_size,
                              hipStream_t stream) {
    const float* x  = (const float*)d_in[0];
    const float* Wq = (const float*)d_in[1];
    const float* Wk = (const float*)d_in[2];
    const float* Wv = (const float*)d_in[3];
    float* out = (float*)d_out;

    ushort_t* wt  = (ushort_t*)d_ws;                    // 192*1024
    ushort_t* qws = wt  + (size_t)NCAT * C_;            // 8192*64
    ushort_t* kws = qws + (size_t)M_ * HS_;
    ushort_t* vt  = kws + (size_t)M_ * HS_;

    wconv_kernel<<<NCAT * C_ / (256 * 4), 256, 0, stream>>>(Wq, Wk, Wv, wt);
    proj_kernel<<<512, 512, 0, stream>>>(x, wt, qws, kws, vt);
    flash_kernel<<<dim3(64, 4), 1024, 0, stream>>>(qws, kws, vt, out);
}

// Round 6
// 121.339 us; speedup vs baseline: 3.1583x; 1.0061x over previous
//
#include <hip/hip_runtime.h>
#include <math.h>

// Problem constants
#define B_  4
#define T_  2048
#define C_  1024
#define HS_ 64
#define M_  (B_*T_)   // 8192 rows
#define NCAT 192
#define SCALE_ 0.03125f   // C^-0.5

typedef unsigned short ushort_t;
typedef short bf16x8 __attribute__((ext_vector_type(8)));
typedef float f32x4 __attribute__((ext_vector_type(4)));

static __device__ __forceinline__ unsigned short f2bf(float f) {   // RNE (for inputs)
    union { float f; unsigned int u; } c; c.f = f;
    unsigned int u = c.u;
    return (unsigned short)((u + 0x7FFFu + ((u >> 16) & 1u)) >> 16);
}
static __device__ __forceinline__ unsigned short f2bf_fast(float f) { // 2-op round
    union { float f; unsigned int u; } c; c.f = f;
    return (unsigned short)((c.u + 0x8000u) >> 16);
}

// ---------------------------------------------------------------------------
// Kernel 1: W -> wt bf16 transposed [192][1024] (4/thread, 192 blocks).
// ---------------------------------------------------------------------------
__global__ void wconv_kernel(const float* __restrict__ Wq, const float* __restrict__ Wk,
                             const float* __restrict__ Wv, ushort_t* __restrict__ wt) {
    int idx = (blockIdx.x * 256 + threadIdx.x) * 4;   // < 192*1024
    int n = idx >> 10;
    int k0 = idx & 1023;
    const float* W = (n < 64) ? Wq : (n < 128) ? Wk : Wv;
    int nn = n & 63;
    ushort_t o0 = f2bf(W[(k0 + 0) * HS_ + nn]);
    ushort_t o1 = f2bf(W[(k0 + 1) * HS_ + nn]);
    ushort_t o2 = f2bf(W[(k0 + 2) * HS_ + nn]);
    ushort_t o3 = f2bf(W[(k0 + 3) * HS_ + nn]);
    uint2 d;
    d.x = (unsigned)o0 | ((unsigned)o1 << 16);
    d.y = (unsigned)o2 | ((unsigned)o3 << 16);
    *(uint2*)(wt + (size_t)n * C_ + k0) = d;
}

// ---------------------------------------------------------------------------
// Kernel 2: QKV projection, ONE PASS over x. Block = 512 thr = 8 waves =
// 8 K-slices of 128; wave = 16 rows x ALL 192 cols (12 MFMA tiles).
// 3-round LDS tree reduce (49 KB). grid 512 blocks (2/CU).
// Q pre-scaled. V transposed [b][d][t].  (Verified R1/R5 structure.)
// ---------------------------------------------------------------------------
__global__ __launch_bounds__(512, 4) void proj_kernel(const float* __restrict__ x,
    const ushort_t* __restrict__ wt,
    ushort_t* __restrict__ qws, ushort_t* __restrict__ kws, ushort_t* __restrict__ vt) {
    __shared__ __align__(16) f32x4 red[4][12 * 64];   // 49 KB

    int tid  = threadIdx.x;
    int wid  = tid >> 6;       // K-slice 0..7
    int lane = tid & 63;
    int qd   = lane >> 4;
    int lq   = lane & 15;
    int r0   = blockIdx.x * 16;    // 512 rowgroups of 16

    f32x4 acc[12];
    #pragma unroll
    for (int i = 0; i < 12; i++) acc[i] = (f32x4){0.f,0.f,0.f,0.f};

    const float*    xp = x  + (size_t)(r0 + lq) * C_ + wid * 128 + qd * 8;
    const ushort_t* wp = wt + (size_t)lq * C_ + wid * 128 + qd * 8;

    #pragma unroll
    for (int i = 0; i < 4; i++) {
        float4 a0 = *(const float4*)(xp + i * 32);
        float4 a1 = *(const float4*)(xp + i * 32 + 4);
        union { bf16x8 v; ushort_t u[8]; } af;
        af.u[0] = f2bf(a0.x); af.u[1] = f2bf(a0.y); af.u[2] = f2bf(a0.z); af.u[3] = f2bf(a0.w);
        af.u[4] = f2bf(a1.x); af.u[5] = f2bf(a1.y); af.u[6] = f2bf(a1.z); af.u[7] = f2bf(a1.w);
        #pragma unroll
        for (int nt = 0; nt < 12; nt++) {
            bf16x8 bv = *(const bf16x8*)(wp + (size_t)nt * 16 * C_ + i * 32);
            acc[nt] = __builtin_amdgcn_mfma_f32_16x16x32_bf16(af.v, bv, acc[nt], 0, 0, 0);
        }
    }

    // tree reduce 8 -> 4 -> 2 -> 1 through 4 LDS slots
    if (wid >= 4) {
        #pragma unroll
        for (int nt = 0; nt < 12; nt++) red[wid - 4][nt * 64 + lane] = acc[nt];
    }
    __syncthreads();
    if (wid < 4) {
        #pragma unroll
        for (int nt = 0; nt < 12; nt++) acc[nt] += red[wid][nt * 64 + lane];
    }
    __syncthreads();
    if (wid == 2 || wid == 3) {
        #pragma unroll
        for (int nt = 0; nt < 12; nt++) red[wid][nt * 64 + lane] = acc[nt];
    }
    __syncthreads();
    if (wid < 2) {
        #pragma unroll
        for (int nt = 0; nt < 12; nt++) acc[nt] += red[wid + 2][nt * 64 + lane];
    }
    __syncthreads();
    if (wid == 1) {
        #pragma unroll
        for (int nt = 0; nt < 12; nt++) red[0][nt * 64 + lane] = acc[nt];
    }
    __syncthreads();
    if (wid == 0) {
        #pragma unroll
        for (int nt = 0; nt < 12; nt++) {
            acc[nt] += red[0][nt * 64 + lane];
            int outn = nt >> 2;            // 0=Q 1=K 2=V
            int col  = (nt & 3) * 16 + lq; // 0..63
            #pragma unroll
            for (int r = 0; r < 4; r++) {
                int row = r0 + qd * 4 + r;
                float v = acc[nt][r];
                if (outn == 0) v *= SCALE_;           // pre-scale Q
                ushort_t val = f2bf(v);
                if (outn == 0)      qws[(size_t)row * HS_ + col] = val;
                else if (outn == 1) kws[(size_t)row * HS_ + col] = val;
                else {
                    int b = row >> 11, t = row & 2047;
                    vt[((size_t)b * 64 + col) * T_ + t] = val;
                }
            }
        }
    }
}

// ---------------------------------------------------------------------------
// Kernel 3: balanced-pair causal flash, 512-thread blocks (8 waves).
// __launch_bounds__(512,2) -> 256-VGPR budget: kf[8]+vf[8]+S+O+qf all live
// simultaneously (~140 regs) with NO spill, unlike the 1024-thr version
// whose forced 128 cap sat right at the live-set size. Grid (64,4) =
// 256 blocks = 1/CU. Pair (p,127-p): exactly 33 64-key units per block.
// Waves: ts = tile half (0/1), ws = key-slice 0..3 (stride 4 over units).
// 16 global loads (K+V) batched up front per unit (R0-proven pattern).
// fp32 O/lsum tree-reduced 4->2->1 per tile via LDS, direct fp32 out.
// ---------------------------------------------------------------------------
__global__ __launch_bounds__(512, 2) void flash_kernel(const ushort_t* __restrict__ qws,
    const ushort_t* __restrict__ kws, const ushort_t* __restrict__ vt,
    float* __restrict__ out) {
    // pool: during k-loop = per-wave Pw[8][16*72] bf16 (18432 B);
    // after k-loop (sync'd) = f32x4 red[4][4*64] (16384 B) + float lred[4][64]
    __shared__ __align__(16) unsigned char pool[18432];

    int tid  = threadIdx.x;
    int wid  = tid >> 6;      // 0..7
    int lane = tid & 63;
    int qd   = lane >> 4;
    int lq   = lane & 15;
    int ts   = wid >> 2;      // 0 = tile p, 1 = tile 127-p
    int ws   = wid & 3;       // key-slice 0..3

    int batch = blockIdx.y;
    int p     = blockIdx.x;
    int tile  = ts ? (127 - p) : p;
    int q0    = tile * 16;
    int qrow  = q0 + lq;
    int grow  = batch * T_ + qrow;
    int nU    = (tile + 4) >> 2;    // 64-key units covering keys [0, q0+16)

    bf16x8 qf[2];
    #pragma unroll
    for (int st = 0; st < 2; st++)
        qf[st] = *(const bf16x8*)(qws + (size_t)grow * HS_ + st * 32 + qd * 8);

    float lsum = 0.f;
    f32x4 O[4];
    #pragma unroll
    for (int nt = 0; nt < 4; nt++) O[nt] = (f32x4){0.f,0.f,0.f,0.f};

    ushort_t* pw = (ushort_t*)pool + wid * 1152 + lq * 72;   // stride 72 bf16
    const ushort_t* kp    = kws + (size_t)batch * T_ * HS_;
    const ushort_t* vbase = vt  + (size_t)batch * 64 * T_;

    for (int u = ws; u < nU; u += 4) {
        int kb = u * 64;

        // batched loads: 8 K-frags + 8 V-frags, all 16 independent & in flight
        bf16x8 kf[8], vf[8];
        #pragma unroll
        for (int sub = 0; sub < 4; sub++)
            #pragma unroll
            for (int st = 0; st < 2; st++)
                kf[sub * 2 + st] = *(const bf16x8*)(kp + (size_t)(kb + sub * 16 + lq) * HS_ + st * 32 + qd * 8);
        #pragma unroll
        for (int nt = 0; nt < 4; nt++)
            #pragma unroll
            for (int kk = 0; kk < 2; kk++)
                vf[nt * 2 + kk] = *(const bf16x8*)(vbase + ((size_t)nt * 16 + lq) * T_ + kb + kk * 32 + qd * 8);

        // S^T = K . Q^T (Q pre-scaled): 4 sub-tiles of 16 keys
        f32x4 S[4];
        #pragma unroll
        for (int sub = 0; sub < 4; sub++) {
            f32x4 s = (f32x4){0.f,0.f,0.f,0.f};
            #pragma unroll
            for (int st = 0; st < 2; st++)
                s = __builtin_amdgcn_mfma_f32_16x16x32_bf16(kf[sub * 2 + st], qf[st], s, 0, 0, 0);
            S[sub] = s;
        }

        // P = exp(S); mask only when this 64-key unit can cross the diagonal
        if (kb + 64 > q0) {
            #pragma unroll
            for (int sub = 0; sub < 4; sub++)
                #pragma unroll
                for (int r = 0; r < 4; r++) {
                    int key = kb + sub * 16 + qd * 4 + r;
                    float pv = (key <= qrow) ? __expf(S[sub][r]) : 0.f;
                    S[sub][r] = pv;
                    lsum += pv;
                }
        } else {
            #pragma unroll
            for (int sub = 0; sub < 4; sub++)
                #pragma unroll
                for (int r = 0; r < 4; r++) {
                    float pv = __expf(S[sub][r]);
                    S[sub][r] = pv;
                    lsum += pv;
                }
        }

        // P^T: C-layout -> LDS (4x b64 writes) -> B-layout (2x b128 reads)
        #pragma unroll
        for (int sub = 0; sub < 4; sub++) {
            uint2 d;
            d.x = (unsigned)f2bf_fast(S[sub][0]) | ((unsigned)f2bf_fast(S[sub][1]) << 16);
            d.y = (unsigned)f2bf_fast(S[sub][2]) | ((unsigned)f2bf_fast(S[sub][3]) << 16);
            *(uint2*)(pw + sub * 16 + qd * 4) = d;
        }
        bf16x8 pf0 = *(const bf16x8*)(pw + qd * 8);
        bf16x8 pf1 = *(const bf16x8*)(pw + 32 + qd * 8);

        // O^T += V^T . P^T (K-dim = 64 keys = 2 MFMA k-steps)
        #pragma unroll
        for (int nt = 0; nt < 4; nt++) {
            O[nt] = __builtin_amdgcn_mfma_f32_16x16x32_bf16(vf[nt * 2 + 0], pf0, O[nt], 0, 0, 0);
            O[nt] = __builtin_amdgcn_mfma_f32_16x16x32_bf16(vf[nt * 2 + 1], pf1, O[nt], 0, 0, 0);
        }
    }

    // ---- cross-wave fp32 reduction, 4 -> 2 -> 1 per tile ----
    f32x4* red  = (f32x4*)pool;                  // 4 slots x 256 f32x4 (16 KB)
    float* lred = (float*)(pool + 16384);        // 4 slots x 64 f32
    __syncthreads();                             // Pw fully dead block-wide
    if (ws >= 2) {
        int sl = ts * 2 + (ws - 2);
        f32x4* rs = red + (size_t)sl * 256;
        #pragma unroll
        for (int nt = 0; nt < 4; nt++) rs[nt * 64 + lane] = O[nt];
        lred[sl * 64 + lane] = lsum;
    }
    __syncthreads();
    if (ws < 2) {
        int sl = ts * 2 + ws;
        f32x4* rs = red + (size_t)sl * 256;
        #pragma unroll
        for (int nt = 0; nt < 4; nt++) O[nt] += rs[nt * 64 + lane];
        lsum += lred[sl * 64 + lane];
    }
    __syncthreads();
    if (ws == 1) {
        int sl = ts * 2;
        f32x4* rs = red + (size_t)sl * 256;
        #pragma unroll
        for (int nt = 0; nt < 4; nt++) rs[nt * 64 + lane] = O[nt];
        lred[sl * 64 + lane] = lsum;
    }
    __syncthreads();
    if (ws == 0) {
        int sl = ts * 2;
        f32x4* rs = red + (size_t)sl * 256;
        #pragma unroll
        for (int nt = 0; nt < 4; nt++) O[nt] += rs[nt * 64 + lane];
        lsum += lred[sl * 64 + lane];
        // fold the 4 qd partial row-sums -> full denominator per row
        lsum += __shfl_xor(lsum, 16, 64);
        lsum += __shfl_xor(lsum, 32, 64);
        float li = 1.f / lsum;
        #pragma unroll
        for (int nt = 0; nt < 4; nt++) {
            f32x4 o = O[nt] * li;
            *(f32x4*)(out + (size_t)grow * HS_ + nt * 16 + qd * 4) = o;
        }
    }
}

// ---------------------------------------------------------------------------
extern "C" void kernel_launch(void* const* d_in, const int* in_sizes, int n_in,
                              void* d_out, int out_size, void* d_ws, size_t ws_size,
                              hipStream_t stream) {
    const float* x  = (const float*)d_in[0];
    const float* Wq = (const float*)d_in[1];
    const float* Wk = (const float*)d_in[2];
    const float* Wv = (const float*)d_in[3];
    float* out = (float*)d_out;

    ushort_t* wt  = (ushort_t*)d_ws;                    // 192*1024
    ushort_t* qws = wt  + (size_t)NCAT * C_;            // 8192*64
    ushort_t* kws = qws + (size_t)M_ * HS_;
    ushort_t* vt  = kws + (size_t)M_ * HS_;

    wconv_kernel<<<NCAT * C_ / (256 * 4), 256, 0, stream>>>(Wq, Wk, Wv, wt);
    proj_kernel<<<512, 512, 0, stream>>>(x, wt, qws, kws, vt);
    flash_kernel<<<dim3(64, 4), 512, 0, stream>>>(qws, kws, vt, out);
}